// Round 6
// baseline (125.700 us; speedup 1.0000x reference)
//
#include <hip/hip_runtime.h>

// ContextGuidedTokenShift on MI355X.
// x: (B=8, N=16384, C=576) f32, H=W=128. out = w*shift(x) + (1-w)*x
// Channel slabs (widths all multiples of 16 floats) each have a fixed (dy,dx).
// shifted[y,x] = in[y-dy, x-dx] if in bounds else 0.
//
// R6: 8 floats (2 consecutive float4) per thread. Slab boundaries are all
// multiples of 16 floats, so an aligned 8-float chunk never straddles a slab:
// ONE decompose + ONE (dy,dx) + ONE bounds check + ONE branch region covers
// both float4s (R4's failure was two disjoint branch regions per thread).
// Keep XCD-aware swizzle + NT streaming stores + nibble-packed dy/dx.

#define B_   8
#define HW_  128
#define N_   16384      // HW_*HW_
#define C_   576
#define C8_  72         // C_/8
#define NXCD 8

typedef float f32x4 __attribute__((ext_vector_type(4)));

// nibble s = (d + 2); dy/dx per slab s in [0,16)
#define DY_PACK 0x0404131304221322ULL
#define DX_PACK 0x4004311322042213ULL

__global__ __launch_bounds__(256) void cgts_kernel(const float* __restrict__ in,
                                                   const float* __restrict__ wptr,
                                                   float* __restrict__ out) {
    // XCD-aware swizzle: grid = 36864 blocks, divisible by 8 -> bijective.
    const int bid = blockIdx.x;
    const int swz = (bid & (NXCD - 1)) * (int)(gridDim.x / NXCD) + (bid >> 3);
    const int i8  = swz * 256 + (int)threadIdx.x;   // 8-float chunk index

    const float w   = wptr[0];
    const float omw = 1.0f - w;

    // decompose chunk index -> (b, token, channel)
    const int c8 = i8 % C8_;           // magic-mul division
    const int t  = i8 / C8_;           // b*N + n
    const int n  = t & (N_ - 1);
    const int b  = t >> 14;            // N_ = 2^14
    const int y  = n >> 7;             // HW_ = 2^7
    const int xc = n & (HW_ - 1);
    const int c  = c8 << 3;

    // slab index -> offset (pure VALU via packed nibbles)
    int s;
    if (c < 256)      s = c >> 6;
    else if (c < 512) s = 4 + ((c - 256) >> 5);
    else              s = 12 + ((c - 512) >> 4);
    const int sh4 = s << 2;
    const int dy = (int)((DY_PACK >> sh4) & 0xF) - 2;
    const int dx = (int)((DX_PACK >> sh4) & 0xF) - 2;

    // self load: 32B contiguous per lane (2 x dwordx4, shared base)
    const size_t f = (size_t)i8 * 8;
    const f32x4 self0 = *reinterpret_cast<const f32x4*>(in + f);
    const f32x4 self1 = *reinterpret_cast<const f32x4*>(in + f + 4);

    const int sy = y - dy;
    const int sx = xc - dx;
    f32x4 sh0 = (f32x4){0.f, 0.f, 0.f, 0.f};
    f32x4 sh1 = (f32x4){0.f, 0.f, 0.f, 0.f};
    if ((unsigned)sy < (unsigned)HW_ && (unsigned)sx < (unsigned)HW_) {
        const size_t sidx = ((size_t)(b * N_ + (sy << 7) + sx)) * C_ + c;
        sh0 = *reinterpret_cast<const f32x4*>(in + sidx);
        sh1 = *reinterpret_cast<const f32x4*>(in + sidx + 4);
    }

    f32x4 o0, o1;
    o0.x = w * sh0.x + omw * self0.x;
    o0.y = w * sh0.y + omw * self0.y;
    o0.z = w * sh0.z + omw * self0.z;
    o0.w = w * sh0.w + omw * self0.w;
    o1.x = w * sh1.x + omw * self1.x;
    o1.y = w * sh1.y + omw * self1.y;
    o1.z = w * sh1.z + omw * self1.z;
    o1.w = w * sh1.w + omw * self1.w;
    // streaming stores: output is never re-read; keep L2/L3 for the input
    __builtin_nontemporal_store(o0, reinterpret_cast<f32x4*>(out + f));
    __builtin_nontemporal_store(o1, reinterpret_cast<f32x4*>(out + f + 4));
}

extern "C" void kernel_launch(void* const* d_in, const int* in_sizes, int n_in,
                              void* d_out, int out_size, void* d_ws, size_t ws_size,
                              hipStream_t stream) {
    const float* x = (const float*)d_in[0];
    const float* w = (const float*)d_in[1];
    float* out = (float*)d_out;

    const int total8 = B_ * N_ * C8_;          // 9,437,184 8-float chunks
    const int blocks = total8 / 256;           // 36,864 (exact, divisible by 8)
    cgts_kernel<<<blocks, 256, 0, stream>>>(x, w, out);
}

// Round 7
// 111.349 us; speedup vs baseline: 1.1289x; 1.1289x over previous
//
#include <hip/hip_runtime.h>

// ContextGuidedTokenShift on MI355X.
// x: (B=8, N=16384, C=576) f32, H=W=128. out = w*shift(x) + (1-w)*x
// Channel slabs (widths all multiples of 16 floats) each have a fixed (dy,dx).
// shifted[y,x] = in[y-dy, x-dx] if in bounds else 0.
//
// R7: R5 structure (1 float4/thread, lane-contiguous 16B — both wider-
// per-thread variants R4/R6 regressed) with ONE isolated change: plain
// store instead of nontemporal. Tests whether NT-store (L2 bypass) was
// helping (input residency) or hurting (no write aggregation).
// Keep XCD-aware swizzle + nibble-packed dy/dx.

#define B_   8
#define HW_  128
#define N_   16384      // HW_*HW_
#define C_   576
#define C4_  144        // C_/4
#define NXCD 8

typedef float f32x4 __attribute__((ext_vector_type(4)));

// nibble s = (d + 2); dy/dx per slab s in [0,16)
#define DY_PACK 0x0404131304221322ULL
#define DX_PACK 0x4004311322042213ULL

__global__ __launch_bounds__(256) void cgts_kernel(const float* __restrict__ in,
                                                   const float* __restrict__ wptr,
                                                   float* __restrict__ out) {
    // XCD-aware swizzle: grid = 73728 blocks, divisible by 8 -> bijective.
    const int bid = blockIdx.x;
    const int swz = (bid & (NXCD - 1)) * (int)(gridDim.x / NXCD) + (bid >> 3);
    const int idx = swz * 256 + (int)threadIdx.x;   // float4 index

    const float w   = wptr[0];
    const float omw = 1.0f - w;

    // decompose flat float4 index -> (b, token, channel4)
    const int c4 = idx % C4_;          // magic-mul division
    const int t  = idx / C4_;          // b*N + n
    const int n  = t & (N_ - 1);
    const int b  = t >> 14;            // N_ = 2^14
    const int y  = n >> 7;             // HW_ = 2^7
    const int xc = n & (HW_ - 1);
    const int c  = c4 << 2;

    // slab index -> offset (pure VALU via packed nibbles)
    int s;
    if (c < 256)      s = c >> 6;
    else if (c < 512) s = 4 + ((c - 256) >> 5);
    else              s = 12 + ((c - 512) >> 4);
    const int sh4 = s << 2;
    const int dy = (int)((DY_PACK >> sh4) & 0xF) - 2;
    const int dx = (int)((DX_PACK >> sh4) & 0xF) - 2;

    // self load: flat float index = 4*idx (contiguous within each XCD chunk)
    const f32x4 self = *reinterpret_cast<const f32x4*>(in + (size_t)idx * 4);

    const int sy = y - dy;
    const int sx = xc - dx;
    f32x4 sh = (f32x4){0.f, 0.f, 0.f, 0.f};
    if ((unsigned)sy < (unsigned)HW_ && (unsigned)sx < (unsigned)HW_) {
        const size_t sidx = ((size_t)(b * N_ + (sy << 7) + sx)) * C_ + c;
        sh = *reinterpret_cast<const f32x4*>(in + sidx);
    }

    f32x4 o;
    o.x = w * sh.x + omw * self.x;
    o.y = w * sh.y + omw * self.y;
    o.z = w * sh.z + omw * self.z;
    o.w = w * sh.w + omw * self.w;
    // plain store (R7 A/B: NT-store removed)
    *reinterpret_cast<f32x4*>(out + (size_t)idx * 4) = o;
}

extern "C" void kernel_launch(void* const* d_in, const int* in_sizes, int n_in,
                              void* d_out, int out_size, void* d_ws, size_t ws_size,
                              hipStream_t stream) {
    const float* x = (const float*)d_in[0];
    const float* w = (const float*)d_in[1];
    float* out = (float*)d_out;

    const int total4 = B_ * N_ * C4_;          // 18,874,368 float4 chunks
    const int blocks = total4 / 256;           // 73,728 (exact, divisible by 8)
    cgts_kernel<<<blocks, 256, 0, stream>>>(x, w, out);
}